// Round 14
// baseline (76.820 us; speedup 1.0000x reference)
//
#include <hip/hip_runtime.h>

#define M_DIM 64
#define K_DIM 8192
#define N_DIM 8192
#define QB 32
#define NT 64               // N columns per block
#define KC 64               // K per stage (2 quant blocks)
#define SPLITS 2
#define KSPLIT (K_DIM / SPLITS)    // 4096
#define NSTAGE (KSPLIT / KC)       // 64

typedef __attribute__((ext_vector_type(8))) short short8;     // MFMA A/B frag
typedef __attribute__((ext_vector_type(8))) unsigned short ushort8;
typedef __attribute__((ext_vector_type(4))) float f32x4;

static_assert(NSTAGE * KC == KSPLIT, "split must tile");

// f32 -> bf16 round-to-nearest-even
__device__ __forceinline__ unsigned short f2bf(float f) {
    unsigned u = __builtin_bit_cast(unsigned, f);
    u += 0x7fffu + ((u >> 16) & 1u);
    return (unsigned short)(u >> 16);
}

// Fallback path only: clears poison with bias; qgemm<false> atomicAdds on top.
__global__ __launch_bounds__(256) void bias_init(const float* __restrict__ bias,
                                                 float* __restrict__ out) {
    int i = (blockIdx.x * 256 + threadIdx.x) * 4;
    *(f32x4*)(out + i) = *(const f32x4*)(bias + (i & (N_DIM - 1)));
}

// R12 champion (59.4us) verbatim; SINGLE delta: SPLITS 4->2 -> grid 256 =
// exactly 1 block/CU. Tests whether 2-blocks-sharing-a-CU interference
// (LDS issue, bank traffic, drain convoy coupling) is the plateau mechanism.
template <bool PART>
__global__ __launch_bounds__(256, 2) void qgemm(
    const float* __restrict__ x,       // [M][K]
    const float* __restrict__ scales,  // [K/QB][N]
    const float* __restrict__ zeros,   // [K/QB][N]
    const int*   __restrict__ qw,      // [K][N], values 0..255
    float*       __restrict__ outp)    // PART ? [SPLITS][M][N] : [M][N]
{
    __shared__ unsigned short lq[2][NT][72];   // [n][k] bf16, 144B rows
    __shared__ unsigned short lx[2][M_DIM][72];

    const int tid  = threadIdx.x;
    const int lane = tid & 63;
    const int w    = tid >> 6;          // wave 0..3, owns cols [16w,16w+16)

    const int n0 = blockIdx.x * NT;
    const int k0 = blockIdx.y * KSPLIT;

    const int qn   = n0 + lane;         // this thread's weight column
    const int xrow = tid >> 2;          // x staging: row 0..63
    const int xcol = (tid & 3) * 16;    // 16 k's per thread

    int   qv[16];
    float sv0, sv1, zv0, zv1;
    f32x4 xv[4];

    auto load_stage = [&](int kk) {
        #pragma unroll
        for (int s = 0; s < 4; ++s)
            #pragma unroll
            for (int j = 0; j < 4; ++j)
                qv[s * 4 + j] = qw[(size_t)(kk + 16 * s + 4 * w + j) * N_DIM + qn];
        const int b0 = kk >> 5;
        sv0 = scales[(size_t)b0 * N_DIM + qn];
        sv1 = scales[(size_t)(b0 + 1) * N_DIM + qn];
        zv0 = zeros[(size_t)b0 * N_DIM + qn];
        zv1 = zeros[(size_t)(b0 + 1) * N_DIM + qn];
        #pragma unroll
        for (int i = 0; i < 4; ++i)
            xv[i] = *(const f32x4*)(x + (size_t)xrow * K_DIM + kk + xcol + 4 * i);
    };

    load_stage(k0);

    f32x4 acc[4];
    #pragma unroll
    for (int r = 0; r < 4; ++r) acc[r] = (f32x4){0.f, 0.f, 0.f, 0.f};

    for (int t = 0; t < NSTAGE; ++t) {
        const int cur = t & 1;

        const float nz0 = -sv0 * zv0, nz1 = -sv1 * zv1;
        const float s0r = sv0, s1r = sv1;
        uint2 qd[4];
        #pragma unroll
        for (int s = 0; s < 4; ++s) {
            const float sc = (s < 2) ? s0r : s1r;
            const float nz = (s < 2) ? nz0 : nz1;
            unsigned short h0 = f2bf(fmaf((float)qv[s * 4 + 0], sc, nz));
            unsigned short h1 = f2bf(fmaf((float)qv[s * 4 + 1], sc, nz));
            unsigned short h2 = f2bf(fmaf((float)qv[s * 4 + 2], sc, nz));
            unsigned short h3 = f2bf(fmaf((float)qv[s * 4 + 3], sc, nz));
            qd[s].x = (unsigned)h0 | ((unsigned)h1 << 16);
            qd[s].y = (unsigned)h2 | ((unsigned)h3 << 16);
        }
        ushort8 xw0, xw1;
        #pragma unroll
        for (int e = 0; e < 4; ++e) {
            xw0[e]     = f2bf(xv[0][e]);
            xw0[4 + e] = f2bf(xv[1][e]);
            xw1[e]     = f2bf(xv[2][e]);
            xw1[4 + e] = f2bf(xv[3][e]);
        }

        if (t + 1 < NSTAGE) load_stage(k0 + (t + 1) * KC);

        #pragma unroll
        for (int s = 0; s < 4; ++s)
            *(uint2*)&lq[cur][lane][16 * s + 4 * w] = qd[s];
        *(ushort8*)&lx[cur][xrow][xcol]     = xw0;
        *(ushort8*)&lx[cur][xrow][xcol + 8] = xw1;

        __syncthreads();

        #pragma unroll
        for (int c = 0; c < 2; ++c) {
            const short8 bf = *(const short8*)&lq[cur][16 * w + (lane & 15)]
                                                [32 * c + 8 * (lane >> 4)];
            #pragma unroll
            for (int r = 0; r < 4; ++r) {
                const short8 af = *(const short8*)&lx[cur][16 * r + (lane & 15)]
                                                    [32 * c + 8 * (lane >> 4)];
                acc[r] = __builtin_amdgcn_mfma_f32_16x16x32_bf16(af, bf, acc[r], 0, 0, 0);
            }
        }
    }

    // epilogue: C layout col=lane&15, row=4*(lane>>4)+e (validated)
    const int cn = n0 + 16 * w + (lane & 15);
    if (PART) {
        float* po = outp + (size_t)blockIdx.y * (M_DIM * (size_t)N_DIM);
        #pragma unroll
        for (int r = 0; r < 4; ++r) {
            const int m = 16 * r + 4 * (lane >> 4);
            #pragma unroll
            for (int e = 0; e < 4; ++e)
                po[(size_t)(m + e) * N_DIM + cn] = acc[r][e];
        }
    } else {
        #pragma unroll
        for (int r = 0; r < 4; ++r) {
            const int m = 16 * r + 4 * (lane >> 4);
            #pragma unroll
            for (int e = 0; e < 4; ++e)
                atomicAdd(outp + (size_t)(m + e) * N_DIM + cn, acc[r][e]);
        }
    }
}

// out = bias + sum of SPLITS partials. Fully overwrites d_out every call.
__global__ __launch_bounds__(256) void reduce_bias(const float* __restrict__ part,
                                                   const float* __restrict__ bias,
                                                   float* __restrict__ out) {
    int i = (blockIdx.x * 256 + threadIdx.x) * 4;
    f32x4 s = *(const f32x4*)(bias + (i & (N_DIM - 1)));
    #pragma unroll
    for (int sp = 0; sp < SPLITS; ++sp)
        s += *(const f32x4*)(part + (size_t)sp * (M_DIM * (size_t)N_DIM) + i);
    *(f32x4*)(out + i) = s;
}

extern "C" void kernel_launch(void* const* d_in, const int* in_sizes, int n_in,
                              void* d_out, int out_size, void* d_ws, size_t ws_size,
                              hipStream_t stream) {
    const float* x      = (const float*)d_in[0];
    const float* scales = (const float*)d_in[1];
    const float* zeros  = (const float*)d_in[2];
    const float* bias   = (const float*)d_in[3];
    const int*   qw     = (const int*)d_in[4];
    float* out  = (float*)d_out;
    float* part = (float*)d_ws;

    const size_t need = (size_t)SPLITS * M_DIM * N_DIM * sizeof(float);  // 4 MB

    if (ws_size >= need) {
        qgemm<true><<<dim3(N_DIM / NT, SPLITS), 256, 0, stream>>>(
            x, scales, zeros, qw, part);
        reduce_bias<<<dim3((M_DIM * N_DIM) / 1024), 256, 0, stream>>>(part, bias, out);
    } else {
        bias_init<<<dim3((M_DIM * N_DIM) / 1024), 256, 0, stream>>>(bias, out);
        qgemm<false><<<dim3(N_DIM / NT, SPLITS), 256, 0, stream>>>(
            x, scales, zeros, qw, out);
    }
}

// Round 15
// 65.180 us; speedup vs baseline: 1.1786x; 1.1786x over previous
//
#include <hip/hip_runtime.h>

#define M_DIM 64
#define K_DIM 8192
#define N_DIM 8192
#define QB 32
#define NT 64               // N columns per block
#define KC 64               // K per stage (2 quant blocks)
#define SPLITS 4
#define KSPLIT (K_DIM / SPLITS)    // 2048
#define NSTAGE (KSPLIT / KC)       // 32

typedef __attribute__((ext_vector_type(8))) short short8;     // MFMA A/B frag
typedef __attribute__((ext_vector_type(8))) unsigned short ushort8;
typedef __attribute__((ext_vector_type(4))) float f32x4;
typedef __attribute__((ext_vector_type(4))) unsigned int u32x4;

static_assert(NSTAGE * KC == KSPLIT, "split must tile");

// f32 -> bf16 round-to-nearest-even
__device__ __forceinline__ unsigned short f2bf(float f) {
    unsigned u = __builtin_bit_cast(unsigned, f);
    u += 0x7fffu + ((u >> 16) & 1u);
    return (unsigned short)(u >> 16);
}

// Fallback path only: clears poison with bias; qgemm<false,false> adds on top.
__global__ __launch_bounds__(256) void bias_init(const float* __restrict__ bias,
                                                 float* __restrict__ out) {
    int i = (blockIdx.x * 256 + threadIdx.x) * 4;
    *(f32x4*)(out + i) = *(const f32x4*)(bias + (i & (N_DIM - 1)));
}

// One-shot x f32 -> bf16 (1 MB working set; halves the L2 footprint we must
// keep resident under the 256MB weight stream).
__global__ __launch_bounds__(256) void xcvt(const float* __restrict__ x,
                                            unsigned short* __restrict__ xb) {
    int i = (blockIdx.x * 256 + threadIdx.x) * 8;
    f32x4 a = *(const f32x4*)(x + i);
    f32x4 b = *(const f32x4*)(x + i + 4);
    ushort8 o;
    #pragma unroll
    for (int e = 0; e < 4; ++e) { o[e] = f2bf(a[e]); o[4 + e] = f2bf(b[e]); }
    *(ushort8*)(xb + i) = o;
}

// R12 champion core. Deltas (all aimed at x L2 residency):
//  - weight/scale/zero loads are nontemporal (stream through L2, don't evict x)
//  - x staged from bf16 xb (cached loads)
//  - grid is 1-D; block -> (bx,by) remapped so each XCD (= linear%8) hosts
//    blocks of ONE K-split pair: per-XCD x working set 0.25MB, L2-resident.
template <bool XBF, bool PART>
__global__ __launch_bounds__(256, 2) void qgemm(
    const float* __restrict__ x,             // [M][K] f32 (fallback)
    const unsigned short* __restrict__ xb,   // [M][K] bf16 (main)
    const float* __restrict__ scales,        // [K/QB][N]
    const float* __restrict__ zeros,         // [K/QB][N]
    const int*   __restrict__ qw,            // [K][N], 0..255
    float*       __restrict__ outp)          // PART ? [SPLITS][M][N] : [M][N]
{
    __shared__ unsigned short lq[2][NT][72];   // [n][k] bf16, 144B rows
    __shared__ unsigned short lx[2][M_DIM][72];

    const int tid  = threadIdx.x;
    const int lane = tid & 63;
    const int w    = tid >> 6;          // wave 0..3, owns cols [16w,16w+16)

    // XCD-aware remap: L%8 = XCD; y=(L%8)>>1 -> each K-split pinned to 2 XCDs.
    const int L  = blockIdx.x;
    const int by = (L & 7) >> 1;
    const int bx = (L >> 3) * 2 + (L & 1);

    const int n0 = bx * NT;
    const int k0 = by * KSPLIT;

    const int qn   = n0 + lane;         // this thread's weight column
    const int xrow = tid >> 2;          // x staging: row 0..63
    const int xcol = (tid & 3) * 16;    // 16 k's per thread

    int   qv[16];
    float sv0, sv1, zv0, zv1;
    u32x4 xv[2];                        // 16 bf16 (XBF)
    f32x4 xf[4];                        // 16 f32 (fallback)

    auto load_stage = [&](int kk) {
        #pragma unroll
        for (int s = 0; s < 4; ++s)
            #pragma unroll
            for (int j = 0; j < 4; ++j)
                qv[s * 4 + j] = __builtin_nontemporal_load(
                    qw + (size_t)(kk + 16 * s + 4 * w + j) * N_DIM + qn);
        const int b0 = kk >> 5;
        sv0 = __builtin_nontemporal_load(scales + (size_t)b0 * N_DIM + qn);
        sv1 = __builtin_nontemporal_load(scales + (size_t)(b0 + 1) * N_DIM + qn);
        zv0 = __builtin_nontemporal_load(zeros  + (size_t)b0 * N_DIM + qn);
        zv1 = __builtin_nontemporal_load(zeros  + (size_t)(b0 + 1) * N_DIM + qn);
        if (XBF) {
            const unsigned short* xp = xb + (size_t)xrow * K_DIM + kk + xcol;
            xv[0] = *(const u32x4*)xp;
            xv[1] = *(const u32x4*)(xp + 8);
        } else {
            const float* xp = x + (size_t)xrow * K_DIM + kk + xcol;
            #pragma unroll
            for (int i = 0; i < 4; ++i) xf[i] = *(const f32x4*)(xp + 4 * i);
        }
    };

    load_stage(k0);

    f32x4 acc[4];
    #pragma unroll
    for (int r = 0; r < 4; ++r) acc[r] = (f32x4){0.f, 0.f, 0.f, 0.f};

    for (int t = 0; t < NSTAGE; ++t) {
        const int cur = t & 1;

        const float nz0 = -sv0 * zv0, nz1 = -sv1 * zv1;
        const float s0r = sv0, s1r = sv1;
        uint2 qd[4];
        #pragma unroll
        for (int s = 0; s < 4; ++s) {
            const float sc = (s < 2) ? s0r : s1r;
            const float nz = (s < 2) ? nz0 : nz1;
            unsigned short h0 = f2bf(fmaf((float)qv[s * 4 + 0], sc, nz));
            unsigned short h1 = f2bf(fmaf((float)qv[s * 4 + 1], sc, nz));
            unsigned short h2 = f2bf(fmaf((float)qv[s * 4 + 2], sc, nz));
            unsigned short h3 = f2bf(fmaf((float)qv[s * 4 + 3], sc, nz));
            qd[s].x = (unsigned)h0 | ((unsigned)h1 << 16);
            qd[s].y = (unsigned)h2 | ((unsigned)h3 << 16);
        }
        u32x4 xw0, xw1;
        if (XBF) {
            xw0 = xv[0];
            xw1 = xv[1];
        } else {
            ushort8 a, b;
            #pragma unroll
            for (int e = 0; e < 4; ++e) {
                a[e]     = f2bf(xf[0][e]);
                a[4 + e] = f2bf(xf[1][e]);
                b[e]     = f2bf(xf[2][e]);
                b[4 + e] = f2bf(xf[3][e]);
            }
            xw0 = __builtin_bit_cast(u32x4, a);
            xw1 = __builtin_bit_cast(u32x4, b);
        }

        if (t + 1 < NSTAGE) load_stage(k0 + (t + 1) * KC);

        #pragma unroll
        for (int s = 0; s < 4; ++s)
            *(uint2*)&lq[cur][lane][16 * s + 4 * w] = qd[s];
        *(u32x4*)&lx[cur][xrow][xcol]     = xw0;
        *(u32x4*)&lx[cur][xrow][xcol + 8] = xw1;

        __syncthreads();

        #pragma unroll
        for (int c = 0; c < 2; ++c) {
            const short8 bf = *(const short8*)&lq[cur][16 * w + (lane & 15)]
                                                [32 * c + 8 * (lane >> 4)];
            #pragma unroll
            for (int r = 0; r < 4; ++r) {
                const short8 af = *(const short8*)&lx[cur][16 * r + (lane & 15)]
                                                    [32 * c + 8 * (lane >> 4)];
                acc[r] = __builtin_amdgcn_mfma_f32_16x16x32_bf16(af, bf, acc[r], 0, 0, 0);
            }
        }
    }

    // epilogue: C layout col=lane&15, row=4*(lane>>4)+e (validated)
    const int cn = n0 + 16 * w + (lane & 15);
    if (PART) {
        float* po = outp + (size_t)by * (M_DIM * (size_t)N_DIM);
        #pragma unroll
        for (int r = 0; r < 4; ++r) {
            const int m = 16 * r + 4 * (lane >> 4);
            #pragma unroll
            for (int e = 0; e < 4; ++e)
                po[(size_t)(m + e) * N_DIM + cn] = acc[r][e];
        }
    } else {
        #pragma unroll
        for (int r = 0; r < 4; ++r) {
            const int m = 16 * r + 4 * (lane >> 4);
            #pragma unroll
            for (int e = 0; e < 4; ++e)
                atomicAdd(outp + (size_t)(m + e) * N_DIM + cn, acc[r][e]);
        }
    }
}

// out = bias + sum of SPLITS partials. Fully overwrites d_out every call.
__global__ __launch_bounds__(256) void reduce_bias(const float* __restrict__ part,
                                                   const float* __restrict__ bias,
                                                   float* __restrict__ out) {
    int i = (blockIdx.x * 256 + threadIdx.x) * 4;
    f32x4 s = *(const f32x4*)(bias + (i & (N_DIM - 1)));
    #pragma unroll
    for (int sp = 0; sp < SPLITS; ++sp)
        s += *(const f32x4*)(part + (size_t)sp * (M_DIM * (size_t)N_DIM) + i);
    *(f32x4*)(out + i) = s;
}

extern "C" void kernel_launch(void* const* d_in, const int* in_sizes, int n_in,
                              void* d_out, int out_size, void* d_ws, size_t ws_size,
                              hipStream_t stream) {
    const float* x      = (const float*)d_in[0];
    const float* scales = (const float*)d_in[1];
    const float* zeros  = (const float*)d_in[2];
    const float* bias   = (const float*)d_in[3];
    const int*   qw     = (const int*)d_in[4];
    float* out = (float*)d_out;

    unsigned short* xbf = (unsigned short*)d_ws;
    float* part = (float*)((char*)d_ws + (2u << 20));
    const size_t need = (2u << 20) + (size_t)SPLITS * M_DIM * N_DIM * sizeof(float);

    if (ws_size >= need) {
        xcvt<<<dim3((M_DIM * K_DIM) / 2048), 256, 0, stream>>>(x, xbf);
        qgemm<true, true><<<dim3((N_DIM / NT) * SPLITS), 256, 0, stream>>>(
            x, xbf, scales, zeros, qw, part);
        reduce_bias<<<dim3((M_DIM * N_DIM) / 1024), 256, 0, stream>>>(part, bias, out);
    } else {
        bias_init<<<dim3((M_DIM * N_DIM) / 1024), 256, 0, stream>>>(bias, out);
        qgemm<false, false><<<dim3((N_DIM / NT) * SPLITS), 256, 0, stream>>>(
            x, nullptr, scales, zeros, qw, out);
    }
}